// Round 1
// baseline (46.590 us; speedup 1.0000x reference)
//
#include <hip/hip_runtime.h>
#include <hip/hip_bf16.h>

// ShiftAug: out[n,c,h,w] = x[n,c, clip(h + sy - PAD, 0, H-1), clip(w + sx - PAD, 0, W-1)]
// x: (512, 9, 84, 84) f32, shift: (512, 2) i32 with columns (sx, sy), PAD=3.

#define PAD 3
#define N_  512
#define C_  9
#define H_  84
#define W_  84
#define G_  (H_ * (W_ / 4))   // float4 groups per plane = 84*21 = 1764

__global__ __launch_bounds__(256) void shift_aug_kernel(
    const float* __restrict__ x,
    const int*   __restrict__ shift,
    float*       __restrict__ out)
{
    const int plane = blockIdx.x;          // n*C + c
    const int n = plane / C_;
    const int sx = shift[2 * n + 0] - PAD;
    const int sy = shift[2 * n + 1] - PAD;

    const float* __restrict__ xp = x   + (size_t)plane * (H_ * W_);
    float*       __restrict__ op = out + (size_t)plane * (H_ * W_);

    for (int g = threadIdx.x; g < G_; g += blockDim.x) {
        const int h  = g / (W_ / 4);               // magic-multiply by compiler
        const int w0 = (g - h * (W_ / 4)) * 4;

        int ri = h + sy;
        ri = min(max(ri, 0), H_ - 1);
        const float* __restrict__ row = xp + ri * W_;

        int c0 = min(max(w0 + 0 + sx, 0), W_ - 1);
        int c1 = min(max(w0 + 1 + sx, 0), W_ - 1);
        int c2 = min(max(w0 + 2 + sx, 0), W_ - 1);
        int c3 = min(max(w0 + 3 + sx, 0), W_ - 1);

        float4 v;
        v.x = row[c0];
        v.y = row[c1];
        v.z = row[c2];
        v.w = row[c3];

        *reinterpret_cast<float4*>(op + h * W_ + w0) = v;
    }
}

extern "C" void kernel_launch(void* const* d_in, const int* in_sizes, int n_in,
                              void* d_out, int out_size, void* d_ws, size_t ws_size,
                              hipStream_t stream)
{
    const float* x     = (const float*)d_in[0];
    const int*   shift = (const int*)d_in[1];
    float*       out   = (float*)d_out;

    const int planes = N_ * C_;   // 4608 blocks, one (n,c) plane each
    shift_aug_kernel<<<planes, 256, 0, stream>>>(x, shift, out);
}

// Round 3
// 44.535 us; speedup vs baseline: 1.0461x; 1.0461x over previous
//
#include <hip/hip_runtime.h>
#include <hip/hip_bf16.h>

// ShiftAug: out[n,c,h,w] = x[n,c, clip(h + sy - PAD, 0, H-1), clip(w + sx - PAD, 0, W-1)]
// x: (512, 9, 84, 84) f32, shift: (512, 2) i32 with columns (sx, sy), PAD=3.
//
// Memory-bound gather. Key trick: non-temporal stores keep the write stream
// out of L2/LLC so the 130 MB input stays Infinity-Cache-resident -> HBM
// traffic approaches write-only (~130 MB/replay).

#define PAD 3
#define N_  512
#define C_  9
#define H_  84
#define W_  84
#define G_  (H_ * (W_ / 4))   // float4 groups per plane = 84*21 = 1764

typedef float f32x4 __attribute__((ext_vector_type(4)));  // native vector: nt-store OK

__global__ __launch_bounds__(256) void shift_aug_kernel(
    const float* __restrict__ x,
    const int*   __restrict__ shift,
    float*       __restrict__ out)
{
    const int plane = blockIdx.x;          // n*C + c
    const int n = plane / C_;
    const int sx = shift[2 * n + 0] - PAD;
    const int sy = shift[2 * n + 1] - PAD;

    const float* __restrict__ xp = x   + (size_t)plane * (H_ * W_);
    float*       __restrict__ op = out + (size_t)plane * (H_ * W_);

    for (int g = threadIdx.x; g < G_; g += blockDim.x) {
        const int h  = g / (W_ / 4);               // magic-multiply by compiler
        const int w0 = (g - h * (W_ / 4)) * 4;

        int ri = h + sy;
        ri = min(max(ri, 0), H_ - 1);
        const float* __restrict__ row = xp + ri * W_;

        int c0 = min(max(w0 + 0 + sx, 0), W_ - 1);
        int c1 = min(max(w0 + 1 + sx, 0), W_ - 1);
        int c2 = min(max(w0 + 2 + sx, 0), W_ - 1);
        int c3 = min(max(w0 + 3 + sx, 0), W_ - 1);

        f32x4 v;
        v.x = row[c0];
        v.y = row[c1];
        v.z = row[c2];
        v.w = row[c3];

        __builtin_nontemporal_store(v, reinterpret_cast<f32x4*>(op + h * W_ + w0));
    }
}

extern "C" void kernel_launch(void* const* d_in, const int* in_sizes, int n_in,
                              void* d_out, int out_size, void* d_ws, size_t ws_size,
                              hipStream_t stream)
{
    const float* x     = (const float*)d_in[0];
    const int*   shift = (const int*)d_in[1];
    float*       out   = (float*)d_out;

    const int planes = N_ * C_;   // 4608 blocks, one (n,c) plane each
    shift_aug_kernel<<<planes, 256, 0, stream>>>(x, shift, out);
}

// Round 4
// 43.857 us; speedup vs baseline: 1.0623x; 1.0155x over previous
//
#include <hip/hip_runtime.h>
#include <hip/hip_bf16.h>

// ShiftAug: out[n,c,h,w] = x[n,c, clip(h + sy - PAD, 0, H-1), clip(w + sx - PAD, 0, W-1)]
// x: (512, 9, 84, 84) f32, shift: (512, 2) i32 with columns (sx, sy), PAD=3.
//
// Memory-bound gather, ~190 MB HBM traffic/replay (input partially LLC-resident).
// This revision: fully static per-thread schedule with batched independent loads
// (2 groups per step) so the compiler software-pipelines -> more loads in flight
// per wave. Round 3 showed VGPR=8 (no pipelining) at 4.3 TB/s.

#define PAD 3
#define N_  512
#define C_  9
#define H_  84
#define W_  84
#define GPR (W_ / 4)          // float4 groups per row = 21
#define G_  (H_ * GPR)        // groups per plane = 1764 = 256*6 + 228

typedef float f32x4 __attribute__((ext_vector_type(4)));

__device__ __forceinline__ f32x4 gather_group(const float* __restrict__ xp,
                                              int g, int sx, int sy)
{
    const int h  = g / GPR;                 // magic-multiply
    const int w0 = (g - h * GPR) * 4;

    int ri = min(max(h + sy, 0), H_ - 1);
    const float* __restrict__ row = xp + ri * W_;

    const int c0 = min(max(w0 + 0 + sx, 0), W_ - 1);
    const int c1 = min(max(w0 + 1 + sx, 0), W_ - 1);
    const int c2 = min(max(w0 + 2 + sx, 0), W_ - 1);
    const int c3 = min(max(w0 + 3 + sx, 0), W_ - 1);

    f32x4 v;
    v.x = row[c0];
    v.y = row[c1];
    v.z = row[c2];
    v.w = row[c3];
    return v;
}

__device__ __forceinline__ void store_group(float* __restrict__ op, int g, f32x4 v)
{
    const int h  = g / GPR;
    const int w0 = (g - h * GPR) * 4;
    __builtin_nontemporal_store(v, reinterpret_cast<f32x4*>(op + h * W_ + w0));
}

__global__ __launch_bounds__(256) void shift_aug_kernel(
    const float* __restrict__ x,
    const int*   __restrict__ shift,
    float*       __restrict__ out)
{
    const int plane = blockIdx.x;          // n*C + c
    const int n = plane / C_;
    const int sx = shift[2 * n + 0] - PAD;
    const int sy = shift[2 * n + 1] - PAD;

    const float* __restrict__ xp = x   + (size_t)plane * (H_ * W_);
    float*       __restrict__ op = out + (size_t)plane * (H_ * W_);

    const int tid = threadIdx.x;

    // 6 full rounds of 256 groups, processed as 3 pairs: issue both gathers
    // (8 independent loads) before either store.
    #pragma unroll
    for (int r = 0; r < 3; ++r) {
        const int g0 = tid + (2 * r + 0) * 256;
        const int g1 = tid + (2 * r + 1) * 256;
        f32x4 a = gather_group(xp, g0, sx, sy);
        f32x4 b = gather_group(xp, g1, sx, sy);
        store_group(op, g0, a);
        store_group(op, g1, b);
    }

    // tail: groups 1536 .. 1763 (228 of them)
    if (tid < G_ - 6 * 256) {
        const int g = tid + 6 * 256;
        f32x4 a = gather_group(xp, g, sx, sy);
        store_group(op, g, a);
    }
}

extern "C" void kernel_launch(void* const* d_in, const int* in_sizes, int n_in,
                              void* d_out, int out_size, void* d_ws, size_t ws_size,
                              hipStream_t stream)
{
    const float* x     = (const float*)d_in[0];
    const int*   shift = (const int*)d_in[1];
    float*       out   = (float*)d_out;

    const int planes = N_ * C_;   // 4608 blocks, one (n,c) plane each
    shift_aug_kernel<<<planes, 256, 0, stream>>>(x, shift, out);
}